// Round 6
// baseline (339.620 us; speedup 1.0000x reference)
//
#include <hip/hip_runtime.h>
#include <cstdint>

// Fused attention, B=2 S=2048 E=1024 H=16 d=64.
// R6: attn has NO LDS and NO barriers. K/V MFMA fragments are loaded directly
// from global (contiguous 16B/8B per lane, L1/L2-served; 4 waves per block
// share one (bh,split) K/V stream for L1 reuse). 2-way key split (partials
// combine exactly since there is no online max) doubles wave parallelism;
// fp32 partial O/l in workspace + combine kernel.

typedef __bf16 bf16x8 __attribute__((ext_vector_type(8)));
typedef short s16x4 __attribute__((ext_vector_type(4)));
typedef float f32x4 __attribute__((ext_vector_type(4)));

__device__ __forceinline__ unsigned short f32_to_bf16_rne(float f) {
    unsigned int u = __builtin_bit_cast(unsigned int, f);
    u += 0x7FFF + ((u >> 16) & 1);
    return (unsigned short)(u >> 16);
}

// pack 2 f32 -> 2 bf16 (truncate) in one v_perm_b32
__device__ __forceinline__ unsigned int pack_bf16_trunc(float a, float b) {
    unsigned int ua = __builtin_bit_cast(unsigned int, a);
    unsigned int ub = __builtin_bit_cast(unsigned int, b);
    return __builtin_amdgcn_perm(ub, ua, 0x07060302u);  // [b.hi16 : a.hi16]
}

// async global->LDS, 16B per lane (dest = wave-uniform base + lane*16)
__device__ __forceinline__ void gload16(const void* g, void* l) {
    __builtin_amdgcn_global_load_lds(
        (const __attribute__((address_space(1))) unsigned int*)g,
        (__attribute__((address_space(3))) unsigned int*)l, 16, 0, 0);
}

// One launch converting x (1048576 f4), w_in (786432 f4), w_out (262144 f4).
__global__ void cvt_all(const float* __restrict__ x, const float* __restrict__ wi,
                        const float* __restrict__ wo, unsigned short* __restrict__ xb,
                        unsigned short* __restrict__ wib, unsigned short* __restrict__ wob) {
    int i = blockIdx.x * blockDim.x + threadIdx.x;  // 0 .. 2097151
    const float* src; unsigned short* dst; int off;
    if (i < 1048576)            { src = x;  dst = xb;  off = i; }
    else if (i < 1048576 + 786432) { src = wi; dst = wib; off = i - 1048576; }
    else                        { src = wo; dst = wob; off = i - (1048576 + 786432); }
    float4 v = ((const float4*)src)[off];
    ushort4 o;
    o.x = f32_to_bf16_rne(v.x); o.y = f32_to_bf16_rne(v.y);
    o.z = f32_to_bf16_rne(v.z); o.w = f32_to_bf16_rne(v.w);
    ((ushort4*)dst)[off] = o;
}

// GEMM1: C[4096][3072] = X[4096][1024] * W[3072][1024]^T + bias
// Epilogue routes Q (scaled, log2 domain), K packed per-head, V transposed.
__launch_bounds__(256)
__global__ void gemm_qkv(const unsigned short* __restrict__ X,
                         const unsigned short* __restrict__ W,
                         const float* __restrict__ bias,
                         unsigned short* __restrict__ Qp,
                         unsigned short* __restrict__ Kp,
                         unsigned short* __restrict__ Vt) {
    __shared__ __align__(16) unsigned short As[128 * 32];
    __shared__ __align__(16) unsigned short Bs[128 * 32];
    const int t = threadIdx.x;
    const int w = t >> 6, lane = t & 63, quad = lane >> 4, l16 = lane & 15;
    const int wm = (w >> 1) * 64, wn = (w & 1) * 64;
    const int m0 = blockIdx.y * 128, n0 = blockIdx.x * 128;

    f32x4 acc[4][4] = {};

    for (int kt = 0; kt < 1024; kt += 32) {
        __syncthreads();
#pragma unroll
        for (int i = 0; i < 2; ++i) {
            int c = t + 256 * i;                 // chunk 0..511 (16B each)
            int r = c >> 2, cc = (c & 3) * 8;
            gload16(&X[(m0 + r) * 1024 + kt + cc], &As[c * 8]);
            gload16(&W[(n0 + r) * 1024 + kt + cc], &Bs[c * 8]);
        }
        __syncthreads();
        bf16x8 af[4], bw[4];
#pragma unroll
        for (int mi = 0; mi < 4; ++mi)
            af[mi] = *(const bf16x8*)&As[(wm + mi * 16 + l16) * 32 + quad * 8];
#pragma unroll
        for (int ni = 0; ni < 4; ++ni)
            bw[ni] = *(const bf16x8*)&Bs[(wn + ni * 16 + l16) * 32 + quad * 8];
#pragma unroll
        for (int mi = 0; mi < 4; ++mi)
#pragma unroll
            for (int ni = 0; ni < 4; ++ni)
                acc[mi][ni] = __builtin_amdgcn_mfma_f32_16x16x32_bf16(af[mi], bw[ni], acc[mi][ni], 0, 0, 0);
    }

    const float QSCALE = 0.125f * 1.44269504089f;  // fold 1/sqrt(d) and log2(e)
#pragma unroll
    for (int mi = 0; mi < 4; ++mi) {
#pragma unroll
        for (int ni = 0; ni < 4; ++ni) {
            int col = n0 + wn + ni * 16 + l16;
            float bv = bias[col];
            int which = col >> 10;
            int hc = col & 1023;
            int h = hc >> 6, d = hc & 63;
            int row0 = m0 + wm + mi * 16 + quad * 4;   // 4-aligned, no 2048 cross
            int b = row0 >> 11, s0 = row0 & 2047;
            int bh = b * 16 + h;
            if (which == 2) {
                // V^T: d fixed per lane, 4 consecutive s -> one 8B store
                ushort4 pk;
                pk.x = f32_to_bf16_rne(acc[mi][ni][0] + bv);
                pk.y = f32_to_bf16_rne(acc[mi][ni][1] + bv);
                pk.z = f32_to_bf16_rne(acc[mi][ni][2] + bv);
                pk.w = f32_to_bf16_rne(acc[mi][ni][3] + bv);
                *(ushort4*)&Vt[(bh * 64 + d) * 2048 + s0] = pk;
            } else if (which == 0) {
#pragma unroll
                for (int r = 0; r < 4; ++r)
                    Qp[(bh * 2048 + s0 + r) * 64 + d] =
                        f32_to_bf16_rne((acc[mi][ni][r] + bv) * QSCALE);
            } else {
#pragma unroll
                for (int r = 0; r < 4; ++r)
                    Kp[(bh * 2048 + s0 + r) * 64 + d] = f32_to_bf16_rne(acc[mi][ni][r] + bv);
            }
        }
    }
}

// Flash attention, S^T orientation, no LDS, no barriers, 2-way key split.
// 1 wave = (bh, split, 32 queries) over 1024 keys. 4 waves/block share
// (bh, split) for L1 locality on the K/V stream. No online max (scores
// bounded in log2 domain); partial O (fp32) and l written to workspace.
__launch_bounds__(256, 3)
__global__ void attn_ks(const unsigned short* __restrict__ Qp, const unsigned short* __restrict__ Kp,
                        const unsigned short* __restrict__ Vt,
                        float* __restrict__ Po, float* __restrict__ Pl) {
    const int t = threadIdx.x, w = t >> 6, lane = t & 63, quad = lane >> 4, l16 = lane & 15;
    const int bh = blockIdx.x & 31;
    const int rest = blockIdx.x >> 5;     // 0..31
    const int split = rest & 1;
    const int qg = rest >> 1;             // 0..15
    const int q0 = (qg * 4 + w) * 32;     // wave's 32-query base
    const unsigned short* Qh = Qp + bh * (2048 * 64);
    const unsigned short* Kh = Kp + bh * (2048 * 64);
    const unsigned short* Vh = Vt + bh * (64 * 2048);
    const int k0 = split * 1024;

    // Q as B-operand (K=32): lane holds Q[q = q0+nq*16+l16][d = ks*32+quad*8 ..+7]
    bf16x8 qf[2][2];
#pragma unroll
    for (int nq = 0; nq < 2; ++nq)
#pragma unroll
        for (int ks = 0; ks < 2; ++ks)
            qf[nq][ks] = *(const bf16x8*)&Qh[(q0 + nq * 16 + l16) * 64 + ks * 32 + quad * 8];

    f32x4 o_acc[4][2] = {};   // O^T: [dm][nq], C layout: d=dm*16+quad*4+reg, q=nq*16+l16
    float l_lane[2] = {0.f, 0.f};

    for (int it = 0; it < 16; ++it) {
        const int kt = k0 + it * 64;

        // K fragments straight from global: A[m=key][k=d], 16B/lane
        bf16x8 kf[2][4];
#pragma unroll
        for (int ks = 0; ks < 2; ++ks)
#pragma unroll
            for (int mi = 0; mi < 4; ++mi)
                kf[ks][mi] = *(const bf16x8*)&Kh[(kt + mi * 16 + l16) * 64 + ks * 32 + quad * 8];

        // S^T = K * Q^T  (row = key, col = query), K=32 MFMA
        f32x4 s_acc[4][2] = {};
#pragma unroll
        for (int ks = 0; ks < 2; ++ks)
#pragma unroll
            for (int mi = 0; mi < 4; ++mi)
#pragma unroll
                for (int nq = 0; nq < 2; ++nq)
                    s_acc[mi][nq] = __builtin_amdgcn_mfma_f32_16x16x32_bf16(kf[ks][mi], qf[nq][ks], s_acc[mi][nq], 0, 0, 0);

        // V^T fragments straight from global (issued before the exp2 burst so
        // their latency overlaps it): A[m=d][k=key], 8B/lane
        uint2 av[4][4];
#pragma unroll
        for (int dm = 0; dm < 4; ++dm)
#pragma unroll
            for (int kt4 = 0; kt4 < 4; ++kt4)
                av[dm][kt4] = *(const uint2*)&Vh[(dm * 16 + l16) * 2048 + kt + kt4 * 16 + quad * 4];

        // p = exp2(s) direct; packed s_acc IS the B-operand of the K=16 MFMA
        s16x4 bq[4][2];
#pragma unroll
        for (int nq = 0; nq < 2; ++nq) {
            float rsum = 0.f;
#pragma unroll
            for (int mi = 0; mi < 4; ++mi) {
                float p0 = exp2f(s_acc[mi][nq][0]);
                float p1 = exp2f(s_acc[mi][nq][1]);
                float p2 = exp2f(s_acc[mi][nq][2]);
                float p3 = exp2f(s_acc[mi][nq][3]);
                rsum += (p0 + p1) + (p2 + p3);
                uint2 pk;
                pk.x = pack_bf16_trunc(p0, p1);
                pk.y = pack_bf16_trunc(p2, p3);
                bq[mi][nq] = __builtin_bit_cast(s16x4, pk);
            }
            l_lane[nq] += rsum;
        }

        // O^T += V^T * P^T via 16x16x16 MFMA
#pragma unroll
        for (int dm = 0; dm < 4; ++dm)
#pragma unroll
            for (int kt4 = 0; kt4 < 4; ++kt4) {
                s16x4 avv = __builtin_bit_cast(s16x4, av[dm][kt4]);
#pragma unroll
                for (int nq = 0; nq < 2; ++nq)
                    o_acc[dm][nq] = __builtin_amdgcn_mfma_f32_16x16x16bf16_1k(avv, bq[kt4][nq], o_acc[dm][nq], 0, 0, 0);
            }
    }

    // epilogue: fp32 partials. Po[split][bh][q][d], Pl[split][bh][q]
#pragma unroll
    for (int nq = 0; nq < 2; ++nq) {
        float l = l_lane[nq];
        l += __shfl_xor(l, 16);
        l += __shfl_xor(l, 32);
        int q = q0 + nq * 16 + l16;
        size_t base = ((size_t)(split * 32 + bh) * 2048 + q) * 64;
#pragma unroll
        for (int dm = 0; dm < 4; ++dm)
            *(float4*)&Po[base + dm * 16 + quad * 4] = __builtin_bit_cast(float4, o_acc[dm][nq]);
        if (quad == 0)
            Pl[(split * 32 + bh) * 2048 + q] = l;
    }
}

// Combine: A2[tok][h*64+d] = (O0+O1)/(l0+l1), bf16 out.
__global__ void attn_combine(const float* __restrict__ Po, const float* __restrict__ Pl,
                             unsigned short* __restrict__ A2) {
    int i = blockIdx.x * blockDim.x + threadIdx.x;  // 0 .. 32*2048*16-1
    int bh = i >> 15;
    int rem = i & 32767;
    int q = rem >> 4;
    int d = (rem & 15) * 4;
    size_t base = ((size_t)bh * 2048 + q) * 64 + d;
    const size_t SPLIT = (size_t)32 * 2048 * 64;
    float4 o0 = *(const float4*)&Po[base];
    float4 o1 = *(const float4*)&Po[base + SPLIT];
    float l = Pl[bh * 2048 + q] + Pl[32 * 2048 + bh * 2048 + q];
    float rl = 1.0f / l;
    int tok = (bh >> 4) * 2048 + q;
    int col = (bh & 15) * 64 + d;
    ushort4 o;
    o.x = f32_to_bf16_rne((o0.x + o1.x) * rl);
    o.y = f32_to_bf16_rne((o0.y + o1.y) * rl);
    o.z = f32_to_bf16_rne((o0.z + o1.z) * rl);
    o.w = f32_to_bf16_rne((o0.w + o1.w) * rl);
    *(ushort4*)&A2[(size_t)tok * 1024 + col] = o;
}

// GEMM2: out[4096][1024] = A2[4096][1024] * W[1024][1024]^T + bias (fp32 out)
// 128x64 tiles -> 512 blocks (2/CU, 8 waves/CU).
__launch_bounds__(256)
__global__ void gemm_out_k(const unsigned short* __restrict__ A, const unsigned short* __restrict__ W,
                           const float* __restrict__ bias, float* __restrict__ out) {
    __shared__ __align__(16) unsigned short As[128 * 32];
    __shared__ __align__(16) unsigned short Bs[64 * 32];
    const int t = threadIdx.x;
    const int w = t >> 6, lane = t & 63, quad = lane >> 4, l16 = lane & 15;
    const int wm = (w >> 1) * 64, wn = (w & 1) * 32;
    const int m0 = blockIdx.y * 128, n0 = blockIdx.x * 64;

    f32x4 acc[4][2] = {};

    for (int kt = 0; kt < 1024; kt += 32) {
        __syncthreads();
#pragma unroll
        for (int i = 0; i < 2; ++i) {
            int c = t + 256 * i;
            int r = c >> 2, cc = (c & 3) * 8;
            gload16(&A[(m0 + r) * 1024 + kt + cc], &As[c * 8]);
        }
        {
            int c = t;                            // 0..255 -> Bs 64x32
            int r = c >> 2, cc = (c & 3) * 8;
            gload16(&W[(n0 + r) * 1024 + kt + cc], &Bs[c * 8]);
        }
        __syncthreads();
        bf16x8 af[4], bw[2];
#pragma unroll
        for (int mi = 0; mi < 4; ++mi)
            af[mi] = *(const bf16x8*)&As[(wm + mi * 16 + l16) * 32 + quad * 8];
#pragma unroll
        for (int ni = 0; ni < 2; ++ni)
            bw[ni] = *(const bf16x8*)&Bs[(wn + ni * 16 + l16) * 32 + quad * 8];
#pragma unroll
        for (int mi = 0; mi < 4; ++mi)
#pragma unroll
            for (int ni = 0; ni < 2; ++ni)
                acc[mi][ni] = __builtin_amdgcn_mfma_f32_16x16x32_bf16(af[mi], bw[ni], acc[mi][ni], 0, 0, 0);
    }

#pragma unroll
    for (int mi = 0; mi < 4; ++mi)
#pragma unroll
        for (int ni = 0; ni < 2; ++ni) {
            int col = n0 + wn + ni * 16 + l16;
            float bv = bias[col];
#pragma unroll
            for (int r = 0; r < 4; ++r) {
                int row = m0 + wm + mi * 16 + quad * 4 + r;
                out[row * 1024 + col] = acc[mi][ni][r] + bv;
            }
        }
}

extern "C" void kernel_launch(void* const* d_in, const int* in_sizes, int n_in,
                              void* d_out, int out_size, void* d_ws, size_t ws_size,
                              hipStream_t stream) {
    const float* x     = (const float*)d_in[0];   // [2,2048,1024]
    const float* w_in  = (const float*)d_in[1];   // [3072,1024]
    const float* b_in  = (const float*)d_in[2];   // [3072]
    const float* w_out = (const float*)d_in[3];   // [1024,1024]
    const float* b_out = (const float*)d_in[4];   // [1024]
    float* out = (float*)d_out;

    char* ws = (char*)d_ws;
    unsigned short* xb  = (unsigned short*)(ws);                      // 8.0 MiB
    unsigned short* wib = (unsigned short*)(ws + 8388608);            // 6.0 MiB
    unsigned short* wob = (unsigned short*)(ws + 14680064);           // 2.0 MiB
    unsigned short* Qp  = (unsigned short*)(ws + 16777216);           // 8.0 MiB
    unsigned short* Kp  = (unsigned short*)(ws + 25165824);           // 8.0 MiB
    unsigned short* Vt  = (unsigned short*)(ws + 33554432);           // 8.0 MiB
    unsigned short* A2  = (unsigned short*)(ws + 41943040);           // 8.0 MiB
    float*          Po  = (float*)(ws + 50331648);                    // 32.0 MiB
    float*          Pl  = (float*)(ws + 50331648 + 33554432);         // 0.5 MiB; total ~83 MiB

    cvt_all<<<8192, 256, 0, stream>>>(x, w_in, w_out, xb, wib, wob);
    gemm_qkv<<<dim3(24, 32), 256, 0, stream>>>(xb, wib, b_in, Qp, Kp, Vt);
    attn_ks<<<1024, 256, 0, stream>>>(Qp, Kp, Vt, Po, Pl);
    attn_combine<<<4096, 256, 0, stream>>>(Po, Pl, A2);
    gemm_out_k<<<dim3(16, 32), 256, 0, stream>>>(A2, wob, b_out, out);
}

// Round 7
// 220.608 us; speedup vs baseline: 1.5395x; 1.5395x over previous
//
#include <hip/hip_runtime.h>
#include <cstdint>

// Fused attention, B=2 S=2048 E=1024 H=16 d=64.
// R7: attn = R5's direct-accumulator PV (no P LDS round-trip) but with
// 4 waves/block: Ps removal means a 256-thread block needs only 36.9 KB LDS
// (K/V double-buffer) -> 4 blocks/CU = 16 waves/CU = 4 waves/SIMD, double
// R5's latency hiding. R6's no-LDS experiment reverted (VMEM-latency-bound).

typedef __bf16 bf16x8 __attribute__((ext_vector_type(8)));
typedef short s16x4 __attribute__((ext_vector_type(4)));
typedef float f32x4 __attribute__((ext_vector_type(4)));

__device__ __forceinline__ unsigned short f32_to_bf16_rne(float f) {
    unsigned int u = __builtin_bit_cast(unsigned int, f);
    u += 0x7FFF + ((u >> 16) & 1);
    return (unsigned short)(u >> 16);
}

// pack 2 f32 -> 2 bf16 (truncate) in one v_perm_b32
__device__ __forceinline__ unsigned int pack_bf16_trunc(float a, float b) {
    unsigned int ua = __builtin_bit_cast(unsigned int, a);
    unsigned int ub = __builtin_bit_cast(unsigned int, b);
    return __builtin_amdgcn_perm(ub, ua, 0x07060302u);  // [b.hi16 : a.hi16]
}

// async global->LDS, 16B per lane (dest = wave-uniform base + lane*16)
__device__ __forceinline__ void gload16(const void* g, void* l) {
    __builtin_amdgcn_global_load_lds(
        (const __attribute__((address_space(1))) unsigned int*)g,
        (__attribute__((address_space(3))) unsigned int*)l, 16, 0, 0);
}

// One launch converting x (1048576 f4), w_in (786432 f4), w_out (262144 f4).
__global__ void cvt_all(const float* __restrict__ x, const float* __restrict__ wi,
                        const float* __restrict__ wo, unsigned short* __restrict__ xb,
                        unsigned short* __restrict__ wib, unsigned short* __restrict__ wob) {
    int i = blockIdx.x * blockDim.x + threadIdx.x;  // 0 .. 2097151
    const float* src; unsigned short* dst; int off;
    if (i < 1048576)            { src = x;  dst = xb;  off = i; }
    else if (i < 1048576 + 786432) { src = wi; dst = wib; off = i - 1048576; }
    else                        { src = wo; dst = wob; off = i - (1048576 + 786432); }
    float4 v = ((const float4*)src)[off];
    ushort4 o;
    o.x = f32_to_bf16_rne(v.x); o.y = f32_to_bf16_rne(v.y);
    o.z = f32_to_bf16_rne(v.z); o.w = f32_to_bf16_rne(v.w);
    ((ushort4*)dst)[off] = o;
}

// GEMM1: C[4096][3072] = X[4096][1024] * W[3072][1024]^T + bias
// Epilogue routes Q (scaled, log2 domain), K packed per-head, V transposed.
__launch_bounds__(256)
__global__ void gemm_qkv(const unsigned short* __restrict__ X,
                         const unsigned short* __restrict__ W,
                         const float* __restrict__ bias,
                         unsigned short* __restrict__ Qp,
                         unsigned short* __restrict__ Kp,
                         unsigned short* __restrict__ Vt) {
    __shared__ __align__(16) unsigned short As[128 * 32];
    __shared__ __align__(16) unsigned short Bs[128 * 32];
    const int t = threadIdx.x;
    const int w = t >> 6, lane = t & 63, quad = lane >> 4, l16 = lane & 15;
    const int wm = (w >> 1) * 64, wn = (w & 1) * 64;
    const int m0 = blockIdx.y * 128, n0 = blockIdx.x * 128;

    f32x4 acc[4][4] = {};

    for (int kt = 0; kt < 1024; kt += 32) {
        __syncthreads();
#pragma unroll
        for (int i = 0; i < 2; ++i) {
            int c = t + 256 * i;                 // chunk 0..511 (16B each)
            int r = c >> 2, cc = (c & 3) * 8;
            gload16(&X[(m0 + r) * 1024 + kt + cc], &As[c * 8]);
            gload16(&W[(n0 + r) * 1024 + kt + cc], &Bs[c * 8]);
        }
        __syncthreads();
        bf16x8 af[4], bw[4];
#pragma unroll
        for (int mi = 0; mi < 4; ++mi)
            af[mi] = *(const bf16x8*)&As[(wm + mi * 16 + l16) * 32 + quad * 8];
#pragma unroll
        for (int ni = 0; ni < 4; ++ni)
            bw[ni] = *(const bf16x8*)&Bs[(wn + ni * 16 + l16) * 32 + quad * 8];
#pragma unroll
        for (int mi = 0; mi < 4; ++mi)
#pragma unroll
            for (int ni = 0; ni < 4; ++ni)
                acc[mi][ni] = __builtin_amdgcn_mfma_f32_16x16x32_bf16(af[mi], bw[ni], acc[mi][ni], 0, 0, 0);
    }

    const float QSCALE = 0.125f * 1.44269504089f;  // fold 1/sqrt(d) and log2(e)
#pragma unroll
    for (int mi = 0; mi < 4; ++mi) {
#pragma unroll
        for (int ni = 0; ni < 4; ++ni) {
            int col = n0 + wn + ni * 16 + l16;
            float bv = bias[col];
            int which = col >> 10;
            int hc = col & 1023;
            int h = hc >> 6, d = hc & 63;
            int row0 = m0 + wm + mi * 16 + quad * 4;   // 4-aligned, no 2048 cross
            int b = row0 >> 11, s0 = row0 & 2047;
            int bh = b * 16 + h;
            if (which == 2) {
                // V^T: d fixed per lane, 4 consecutive s -> one 8B store
                ushort4 pk;
                pk.x = f32_to_bf16_rne(acc[mi][ni][0] + bv);
                pk.y = f32_to_bf16_rne(acc[mi][ni][1] + bv);
                pk.z = f32_to_bf16_rne(acc[mi][ni][2] + bv);
                pk.w = f32_to_bf16_rne(acc[mi][ni][3] + bv);
                *(ushort4*)&Vt[(bh * 64 + d) * 2048 + s0] = pk;
            } else if (which == 0) {
#pragma unroll
                for (int r = 0; r < 4; ++r)
                    Qp[(bh * 2048 + s0 + r) * 64 + d] =
                        f32_to_bf16_rne((acc[mi][ni][r] + bv) * QSCALE);
            } else {
#pragma unroll
                for (int r = 0; r < 4; ++r)
                    Kp[(bh * 2048 + s0 + r) * 64 + d] = f32_to_bf16_rne(acc[mi][ni][r] + bv);
            }
        }
    }
}

// Flash attention, S^T orientation, no online max (scores bounded in log2
// domain). 1 block = (bh, 128 queries), 4 waves x 32 queries. PV uses K=16
// MFMA consuming packed s_acc directly (no P LDS round-trip).
#define LDP 72  // padded LDS row: 144 B = 4 mod 32 banks
__launch_bounds__(256, 4)
__global__ void attn(const unsigned short* __restrict__ Qp, const unsigned short* __restrict__ Kp,
                     const unsigned short* __restrict__ Vt, unsigned short* __restrict__ A2) {
    __shared__ __align__(16) unsigned short Ks[2][64 * LDP];  // [buf][key][d]
    __shared__ __align__(16) unsigned short Vs[2][64 * LDP];  // [buf][d][key]
    const int t = threadIdx.x, w = t >> 6, lane = t & 63, quad = lane >> 4, l16 = lane & 15;
    const int bh = blockIdx.x;   // 0..31
    const int qb = blockIdx.y;   // 0..15 (128-query tiles)
    const unsigned short* Qh = Qp + bh * (2048 * 64);
    const unsigned short* Kh = Kp + bh * (2048 * 64);
    const unsigned short* Vh = Vt + bh * (64 * 2048);

    // Q as B-operand (K=32): lane holds Q[q = nq*16+l16][d = ks*32+quad*8 ..+7]
    bf16x8 qf[2][2];
#pragma unroll
    for (int nq = 0; nq < 2; ++nq)
#pragma unroll
        for (int ks = 0; ks < 2; ++ks) {
            int row = qb * 128 + w * 32 + nq * 16 + l16;
            qf[nq][ks] = *(const bf16x8*)&Qh[row * 64 + ks * 32 + quad * 8];
        }

    // staging: 256 threads x 2 16B chunks each for K and V
    const int sr0 = t >> 3, sc0 = (t & 7) * 8;          // chunk t (rows 0..31)
    const int sr1 = sr0 + 32, sc1 = sc0;                // chunk t+256 (rows 32..63)

    f32x4 o_acc[4][2] = {};   // O^T: [dm][nq], C layout: d=dm*16+quad*4+reg, q=nq*16+l16
    float l_lane[2] = {0.f, 0.f};

    // preload tile 0 into buf 0
    {
        *(uint4*)&Ks[0][sr0 * LDP + sc0] = *(const uint4*)&Kh[sr0 * 64 + sc0];
        *(uint4*)&Ks[0][sr1 * LDP + sc1] = *(const uint4*)&Kh[sr1 * 64 + sc1];
        *(uint4*)&Vs[0][sr0 * LDP + sc0] = *(const uint4*)&Vh[sr0 * 2048 + sc0];
        *(uint4*)&Vs[0][sr1 * LDP + sc1] = *(const uint4*)&Vh[sr1 * 2048 + sc1];
    }

    int cur = 0;
    for (int it = 0; it < 32; ++it) {
        __syncthreads();
        uint4 kn0, kn1, vn0, vn1;
        const bool pfetch = (it != 31);
        if (pfetch) {
            int ktn = (it + 1) * 64;
            kn0 = *(const uint4*)&Kh[(ktn + sr0) * 64 + sc0];
            kn1 = *(const uint4*)&Kh[(ktn + sr1) * 64 + sc1];
            vn0 = *(const uint4*)&Vh[sr0 * 2048 + ktn + sc0];
            vn1 = *(const uint4*)&Vh[sr1 * 2048 + ktn + sc1];
        }
        const unsigned short* Kc = Ks[cur];
        const unsigned short* Vc = Vs[cur];

        // S^T = K * Q^T  (row = key, col = query), K=32 MFMA
        f32x4 s_acc[4][2] = {};
#pragma unroll
        for (int ks = 0; ks < 2; ++ks)
#pragma unroll
            for (int mi = 0; mi < 4; ++mi) {
                bf16x8 kf = *(const bf16x8*)&Kc[(mi * 16 + l16) * LDP + ks * 32 + quad * 8];
#pragma unroll
                for (int nq = 0; nq < 2; ++nq)
                    s_acc[mi][nq] = __builtin_amdgcn_mfma_f32_16x16x32_bf16(kf, qf[nq][ks], s_acc[mi][nq], 0, 0, 0);
            }

        // p = exp2(s) direct; packed s_acc IS the B-operand of the K=16 MFMA:
        // B[n=l16][k=quad*4+j] == S^T[key=mi*16+quad*4+r][q=l16]
        s16x4 bq[4][2];
#pragma unroll
        for (int nq = 0; nq < 2; ++nq) {
            float rsum = 0.f;
#pragma unroll
            for (int mi = 0; mi < 4; ++mi) {
                float p0 = exp2f(s_acc[mi][nq][0]);
                float p1 = exp2f(s_acc[mi][nq][1]);
                float p2 = exp2f(s_acc[mi][nq][2]);
                float p3 = exp2f(s_acc[mi][nq][3]);
                rsum += (p0 + p1) + (p2 + p3);
                uint2 pk;
                pk.x = pack_bf16_trunc(p0, p1);
                pk.y = pack_bf16_trunc(p2, p3);
                bq[mi][nq] = __builtin_bit_cast(s16x4, pk);
            }
            l_lane[nq] += rsum;  // per-lane partial; cross-quad reduce deferred
        }

        // O^T += V^T * P^T via 16x16x16 MFMA; A = V^T[d=dm*16+l16][key=kt4*16+quad*4..+3]
#pragma unroll
        for (int dm = 0; dm < 4; ++dm)
#pragma unroll
            for (int kt4 = 0; kt4 < 4; ++kt4) {
                s16x4 av = __builtin_bit_cast(s16x4,
                    *(const uint2*)&Vc[(dm * 16 + l16) * LDP + kt4 * 16 + quad * 4]);
#pragma unroll
                for (int nq = 0; nq < 2; ++nq)
                    o_acc[dm][nq] = __builtin_amdgcn_mfma_f32_16x16x16bf16_1k(av, bq[kt4][nq], o_acc[dm][nq], 0, 0, 0);
            }

        // write prefetched tile into other buffer (overlaps with compute above)
        if (pfetch) {
            *(uint4*)&Ks[cur ^ 1][sr0 * LDP + sc0] = kn0;
            *(uint4*)&Ks[cur ^ 1][sr1 * LDP + sc1] = kn1;
            *(uint4*)&Vs[cur ^ 1][sr0 * LDP + sc0] = vn0;
            *(uint4*)&Vs[cur ^ 1][sr1 * LDP + sc1] = vn1;
        }
        cur ^= 1;
    }

    // epilogue: O^T[d][q] -> A2[tok][h*64+d], 8B packed along d
    const int b = bh >> 4, h = bh & 15;
#pragma unroll
    for (int nq = 0; nq < 2; ++nq) {
        float l = l_lane[nq];
        l += __shfl_xor(l, 16);
        l += __shfl_xor(l, 32);
        float rl = 1.0f / l;
        int s = qb * 128 + w * 32 + nq * 16 + l16;
        int tok = b * 2048 + s;
#pragma unroll
        for (int dm = 0; dm < 4; ++dm) {
            ushort4 o;
            o.x = f32_to_bf16_rne(o_acc[dm][nq][0] * rl);
            o.y = f32_to_bf16_rne(o_acc[dm][nq][1] * rl);
            o.z = f32_to_bf16_rne(o_acc[dm][nq][2] * rl);
            o.w = f32_to_bf16_rne(o_acc[dm][nq][3] * rl);
            *(ushort4*)&A2[tok * 1024 + h * 64 + dm * 16 + quad * 4] = o;
        }
    }
}

// GEMM2: out[4096][1024] = A2[4096][1024] * W[1024][1024]^T + bias (fp32 out)
// 128x64 tiles -> 512 blocks (2/CU, 8 waves/CU).
__launch_bounds__(256)
__global__ void gemm_out_k(const unsigned short* __restrict__ A, const unsigned short* __restrict__ W,
                           const float* __restrict__ bias, float* __restrict__ out) {
    __shared__ __align__(16) unsigned short As[128 * 32];
    __shared__ __align__(16) unsigned short Bs[64 * 32];
    const int t = threadIdx.x;
    const int w = t >> 6, lane = t & 63, quad = lane >> 4, l16 = lane & 15;
    const int wm = (w >> 1) * 64, wn = (w & 1) * 32;
    const int m0 = blockIdx.y * 128, n0 = blockIdx.x * 64;

    f32x4 acc[4][2] = {};

    for (int kt = 0; kt < 1024; kt += 32) {
        __syncthreads();
#pragma unroll
        for (int i = 0; i < 2; ++i) {
            int c = t + 256 * i;
            int r = c >> 2, cc = (c & 3) * 8;
            gload16(&A[(m0 + r) * 1024 + kt + cc], &As[c * 8]);
        }
        {
            int c = t;                            // 0..255 -> Bs 64x32
            int r = c >> 2, cc = (c & 3) * 8;
            gload16(&W[(n0 + r) * 1024 + kt + cc], &Bs[c * 8]);
        }
        __syncthreads();
        bf16x8 af[4], bw[2];
#pragma unroll
        for (int mi = 0; mi < 4; ++mi)
            af[mi] = *(const bf16x8*)&As[(wm + mi * 16 + l16) * 32 + quad * 8];
#pragma unroll
        for (int ni = 0; ni < 2; ++ni)
            bw[ni] = *(const bf16x8*)&Bs[(wn + ni * 16 + l16) * 32 + quad * 8];
#pragma unroll
        for (int mi = 0; mi < 4; ++mi)
#pragma unroll
            for (int ni = 0; ni < 2; ++ni)
                acc[mi][ni] = __builtin_amdgcn_mfma_f32_16x16x32_bf16(af[mi], bw[ni], acc[mi][ni], 0, 0, 0);
    }

#pragma unroll
    for (int mi = 0; mi < 4; ++mi)
#pragma unroll
        for (int ni = 0; ni < 2; ++ni) {
            int col = n0 + wn + ni * 16 + l16;
            float bv = bias[col];
#pragma unroll
            for (int r = 0; r < 4; ++r) {
                int row = m0 + wm + mi * 16 + quad * 4 + r;
                out[row * 1024 + col] = acc[mi][ni][r] + bv;
            }
        }
}

extern "C" void kernel_launch(void* const* d_in, const int* in_sizes, int n_in,
                              void* d_out, int out_size, void* d_ws, size_t ws_size,
                              hipStream_t stream) {
    const float* x     = (const float*)d_in[0];   // [2,2048,1024]
    const float* w_in  = (const float*)d_in[1];   // [3072,1024]
    const float* b_in  = (const float*)d_in[2];   // [3072]
    const float* w_out = (const float*)d_in[3];   // [1024,1024]
    const float* b_out = (const float*)d_in[4];   // [1024]
    float* out = (float*)d_out;

    char* ws = (char*)d_ws;
    unsigned short* xb  = (unsigned short*)(ws);                // 8.0 MiB
    unsigned short* wib = (unsigned short*)(ws + 8388608);      // 6.0 MiB
    unsigned short* wob = (unsigned short*)(ws + 14680064);     // 2.0 MiB
    unsigned short* Qp  = (unsigned short*)(ws + 16777216);     // 8.0 MiB
    unsigned short* Kp  = (unsigned short*)(ws + 25165824);     // 8.0 MiB
    unsigned short* Vt  = (unsigned short*)(ws + 33554432);     // 8.0 MiB
    unsigned short* A2  = (unsigned short*)(ws + 41943040);     // 8.0 MiB; total 48 MiB

    cvt_all<<<8192, 256, 0, stream>>>(x, w_in, w_out, xb, wib, wob);
    gemm_qkv<<<dim3(24, 32), 256, 0, stream>>>(xb, wib, b_in, Qp, Kp, Vt);
    attn<<<dim3(32, 16), 256, 0, stream>>>(Qp, Kp, Vt, A2);
    gemm_out_k<<<dim3(16, 32), 256, 0, stream>>>(A2, wob, b_out, out);
}